// Round 2
// baseline (405.856 us; speedup 1.0000x reference)
//
#include <hip/hip_runtime.h>
#include <hip/hip_bf16.h>

// Round 2 dtype decision: inputs/output are FP32 (reference is jnp.float32;
// the "(bf16,...)" in the harness label is literal template text; all-bf16
// math provably cannot NaN but did => we were reading fp32 bits as bf16).
// Compute path: fp32 -> fp16 convert, fp16 MFMA (same rate as bf16, much
// better precision), fp32 accumulate, fp32 output.

typedef __attribute__((ext_vector_type(8))) _Float16 vhalf8;  // 8 f16 (4 VGPRs)
typedef __attribute__((ext_vector_type(4))) float vfloat4;    // 4 fp32 acc

#define D_MODEL 1024
#define SEQ     2048
#define NB      2
#define NH      16
#define HD      64

// ---------------------------------------------------------------------------
// fp32 -> fp16 elementwise convert, 8 elems/thread.
// ---------------------------------------------------------------------------
__global__ __launch_bounds__(256) void cvt_f32_f16(
    const float* __restrict__ in, _Float16* __restrict__ out) {
  size_t i = ((size_t)blockIdx.x * 256 + threadIdx.x) * 8;
  float4 a = *(const float4*)&in[i];
  float4 b = *(const float4*)&in[i + 4];
  vhalf8 h;
  h[0] = (_Float16)a.x; h[1] = (_Float16)a.y;
  h[2] = (_Float16)a.z; h[3] = (_Float16)a.w;
  h[4] = (_Float16)b.x; h[5] = (_Float16)b.y;
  h[6] = (_Float16)b.z; h[7] = (_Float16)b.w;
  *(vhalf8*)&out[i] = h;
}

// ---------------------------------------------------------------------------
// Transpose + convert: out[c][r] = (f16)in[r][c].  in: R x C fp32.
// ---------------------------------------------------------------------------
__global__ __launch_bounds__(256) void transpose_w(
    const float* __restrict__ in, _Float16* __restrict__ out, int R, int C) {
  __shared__ _Float16 tile[64][65];
  int c0 = blockIdx.x * 64, r0 = blockIdx.y * 64;
  int t = threadIdx.x;
  int tc = t & 63, tr = t >> 6;
#pragma unroll
  for (int p = 0; p < 16; p++) {
    int r = tr + p * 4;
    tile[r][tc] = (_Float16)in[(size_t)(r0 + r) * C + c0 + tc];
  }
  __syncthreads();
#pragma unroll
  for (int p = 0; p < 16; p++) {
    int r = tr + p * 4;  // output row = input col
    out[(size_t)(c0 + r) * R + r0 + tc] = tile[tc][r];
  }
}

// ---------------------------------------------------------------------------
// V [(b,s)][2048 + h*64 + d] slice of QKV (f16) -> Vt [(b,h)][d][s]
// ---------------------------------------------------------------------------
__global__ __launch_bounds__(256) void transpose_v(
    const _Float16* __restrict__ QKV, _Float16* __restrict__ Vt) {
  __shared__ _Float16 tile[64][65];
  int bh = blockIdx.y;  // b*16 + h
  int b = bh >> 4, h = bh & 15;
  int s0 = blockIdx.x * 64;
  int t = threadIdx.x;
  int tc = t & 63, tr = t >> 6;
#pragma unroll
  for (int p = 0; p < 16; p++) {
    int s = tr + p * 4;
    tile[s][tc] = QKV[(size_t)(b * SEQ + s0 + s) * 3072 + 2048 + h * HD + tc];
  }
  __syncthreads();
#pragma unroll
  for (int p = 0; p < 16; p++) {
    int d = tr + p * 4;
    Vt[((size_t)bh * HD + d) * SEQ + s0 + tc] = tile[tc][d];
  }
}

// ---------------------------------------------------------------------------
// f16 GEMM, C[M][N] = A[M][K] @ Bt[N][K]^T.  64x64 tile, 4 waves, BK=32.
// mfma_f32_16x16x32_f16:  A-frag: A[m=lane&15][k=quad*8+j]
//                         B-frag: Bt[n=lane&15][k=quad*8+j]
//                         C/D:    row=quad*4+reg, col=lane&15
// write_f32 selects fp32 (d_out) vs f16 (intermediate) epilogue.
// ---------------------------------------------------------------------------
__global__ __launch_bounds__(256) void gemm_bt(
    const _Float16* __restrict__ A, const _Float16* __restrict__ Bt,
    _Float16* __restrict__ Ch, float* __restrict__ Cf,
    int M, int N, int K, int write_f32) {
  __shared__ _Float16 As[64][40];  // pad 32->40: 16B-aligned rows, 2-way banks only
  __shared__ _Float16 Bs[64][40];
  int m0 = blockIdx.x * 64, n0 = blockIdx.y * 64;
  int t = threadIdx.x;
  int lane = t & 63, wave = t >> 6;
  int wm = (wave >> 1) * 32, wn = (wave & 1) * 32;
  int col = lane & 15, quad = lane >> 4;
  int ldRow = t >> 2, ldChunk = (t & 3) * 8;

  vfloat4 acc[2][2];
#pragma unroll
  for (int i = 0; i < 2; i++)
#pragma unroll
    for (int j = 0; j < 2; j++) {
      acc[i][j][0] = 0.f; acc[i][j][1] = 0.f;
      acc[i][j][2] = 0.f; acc[i][j][3] = 0.f;
    }

  const size_t arow = (size_t)(m0 + ldRow) * K;
  const size_t brow = (size_t)(n0 + ldRow) * K;

  for (int k0 = 0; k0 < K; k0 += 32) {
    *(vhalf8*)&As[ldRow][ldChunk] = *(const vhalf8*)&A[arow + k0 + ldChunk];
    *(vhalf8*)&Bs[ldRow][ldChunk] = *(const vhalf8*)&Bt[brow + k0 + ldChunk];
    __syncthreads();
    vhalf8 a0 = *(const vhalf8*)&As[wm + col][quad * 8];
    vhalf8 a1 = *(const vhalf8*)&As[wm + 16 + col][quad * 8];
    vhalf8 b0 = *(const vhalf8*)&Bs[wn + col][quad * 8];
    vhalf8 b1 = *(const vhalf8*)&Bs[wn + 16 + col][quad * 8];
    acc[0][0] = __builtin_amdgcn_mfma_f32_16x16x32_f16(a0, b0, acc[0][0], 0, 0, 0);
    acc[0][1] = __builtin_amdgcn_mfma_f32_16x16x32_f16(a0, b1, acc[0][1], 0, 0, 0);
    acc[1][0] = __builtin_amdgcn_mfma_f32_16x16x32_f16(a1, b0, acc[1][0], 0, 0, 0);
    acc[1][1] = __builtin_amdgcn_mfma_f32_16x16x32_f16(a1, b1, acc[1][1], 0, 0, 0);
    __syncthreads();
  }

#pragma unroll
  for (int mi = 0; mi < 2; mi++)
#pragma unroll
    for (int ni = 0; ni < 2; ni++)
#pragma unroll
      for (int r = 0; r < 4; r++) {
        int m = m0 + wm + mi * 16 + quad * 4 + r;
        int n = n0 + wn + ni * 16 + col;
        if (write_f32)
          Cf[(size_t)m * N + n] = acc[mi][ni][r];
        else
          Ch[(size_t)m * N + n] = (_Float16)acc[mi][ni][r];
      }
}

// ---------------------------------------------------------------------------
// Flash attention, causal.  1 wave / block, 16-row Q tile, 32-key tiles.
// QKV: [b*S][3072] f16 (Q cols 0..1023, K 1024..2047), Vt: [(b,h)][64][2048]
// Out: Vec[b*S][1024] f16.
// ---------------------------------------------------------------------------
__global__ __launch_bounds__(64) void attn(
    const _Float16* __restrict__ QKV, const _Float16* __restrict__ Vt,
    _Float16* __restrict__ Vec) {
  int blk = blockIdx.x;
  int qt = blk & 127;  // S/16 = 128 q-tiles
  int h = (blk >> 7) & 15;
  int b = blk >> 11;
  int q0 = qt * 16;

  const _Float16* Qb = QKV + (size_t)(b * SEQ) * 3072 + h * HD;
  const _Float16* Kb = QKV + (size_t)(b * SEQ) * 3072 + 1024 + h * HD;
  const _Float16* Vtb = Vt + (size_t)(b * NH + h) * HD * SEQ;

  int lane = threadIdx.x;
  int col = lane & 15, quad = lane >> 4;

  vhalf8 qf0 = *(const vhalf8*)&Qb[(size_t)(q0 + col) * 3072 + quad * 8];
  vhalf8 qf1 = *(const vhalf8*)&Qb[(size_t)(q0 + col) * 3072 + 32 + quad * 8];

  vfloat4 o[4];
#pragma unroll
  for (int i = 0; i < 4; i++) { o[i][0]=0.f; o[i][1]=0.f; o[i][2]=0.f; o[i][3]=0.f; }
  float m_[4] = {-1e30f, -1e30f, -1e30f, -1e30f};
  float l_[4] = {0.f, 0.f, 0.f, 0.f};

  __shared__ _Float16 Plds[16][40];  // 80B row stride keeps 16B-aligned b128 reads

  for (int kb = 0; kb <= q0 + 15; kb += 32) {
    vfloat4 s[2];
#pragma unroll
    for (int hh = 0; hh < 2; hh++) {
      vhalf8 kf0 = *(const vhalf8*)&Kb[(size_t)(kb + hh * 16 + col) * 3072 + quad * 8];
      vhalf8 kf1 = *(const vhalf8*)&Kb[(size_t)(kb + hh * 16 + col) * 3072 + 32 + quad * 8];
      vfloat4 z; z[0]=0.f; z[1]=0.f; z[2]=0.f; z[3]=0.f;
      z = __builtin_amdgcn_mfma_f32_16x16x32_f16(qf0, kf0, z, 0, 0, 0);
      z = __builtin_amdgcn_mfma_f32_16x16x32_f16(qf1, kf1, z, 0, 0, 0);
#pragma unroll
      for (int r = 0; r < 4; r++) z[r] *= 0.125f;  // 1/sqrt(64)
      s[hh] = z;
    }
    if (kb + 31 > q0) {  // diagonal tile: causal mask
#pragma unroll
      for (int hh = 0; hh < 2; hh++)
#pragma unroll
        for (int r = 0; r < 4; r++) {
          int key = kb + hh * 16 + col;
          int q = q0 + quad * 4 + r;
          if (key > q) s[hh][r] = -1e30f;
        }
    }
#pragma unroll
    for (int r = 0; r < 4; r++) {
      float mt = fmaxf(s[0][r], s[1][r]);
#pragma unroll
      for (int msk = 1; msk < 16; msk <<= 1) mt = fmaxf(mt, __shfl_xor(mt, msk, 64));
      float mnew = fmaxf(m_[r], mt);
      float p0 = __expf(s[0][r] - mnew);
      float p1 = __expf(s[1][r] - mnew);
      float alpha = __expf(m_[r] - mnew);
      float rs = p0 + p1;
#pragma unroll
      for (int msk = 1; msk < 16; msk <<= 1) rs += __shfl_xor(rs, msk, 64);
      l_[r] = l_[r] * alpha + rs;
      m_[r] = mnew;
#pragma unroll
      for (int tt = 0; tt < 4; tt++) o[tt][r] *= alpha;
      Plds[quad * 4 + r][col] = (_Float16)p0;
      Plds[quad * 4 + r][16 + col] = (_Float16)p1;
    }
    __syncthreads();
    vhalf8 pf = *(const vhalf8*)&Plds[col][quad * 8];
#pragma unroll
    for (int tt = 0; tt < 4; tt++) {
      vhalf8 vf = *(const vhalf8*)&Vtb[(size_t)(tt * 16 + col) * SEQ + kb + quad * 8];
      o[tt] = __builtin_amdgcn_mfma_f32_16x16x32_f16(pf, vf, o[tt], 0, 0, 0);
    }
    __syncthreads();
  }

  float inv_l[4];
#pragma unroll
  for (int r = 0; r < 4; r++) inv_l[r] = 1.0f / l_[r];
#pragma unroll
  for (int tt = 0; tt < 4; tt++)
#pragma unroll
    for (int r = 0; r < 4; r++) {
      int q = q0 + quad * 4 + r;
      int d = tt * 16 + col;
      Vec[(size_t)(b * SEQ + q) * D_MODEL + h * HD + d] =
          (_Float16)(o[tt][r] * inv_l[r]);
    }
}

// ---------------------------------------------------------------------------
extern "C" void kernel_launch(void* const* d_in, const int* in_sizes, int n_in,
                              void* d_out, int out_size, void* d_ws, size_t ws_size,
                              hipStream_t stream) {
  const float* x  = (const float*)d_in[0];
  const float* Wq = (const float*)d_in[1];
  const float* Wk = (const float*)d_in[2];
  const float* Wv = (const float*)d_in[3];
  const float* Wo = (const float*)d_in[4];
  float* out = (float*)d_out;

  char* ws = (char*)d_ws;
  _Float16* Xh     = (_Float16*)ws;                    // [4096][1024]   8 MiB
  _Float16* Wt_qkv = (_Float16*)(ws + 8388608);        // [3072][1024]   6 MiB
  _Float16* Wot    = (_Float16*)(ws + 14680064);       // [1024][1024]   2 MiB
  _Float16* QKV    = (_Float16*)(ws + 16777216);       // [4096][3072]  24 MiB
  _Float16* Vt     = (_Float16*)(ws + 41943040);       // [32][64][2048] 8 MiB
  _Float16* Vec    = (_Float16*)(ws + 50331648);       // [4096][1024]   8 MiB
  // total ws use: 56 MiB

  dim3 tb(256);
  cvt_f32_f16<<<dim3(2048), tb, 0, stream>>>(x, Xh);  // 4M elems / 8 per thread
  transpose_w<<<dim3(16, 16), tb, 0, stream>>>(Wq, Wt_qkv, 1024, 1024);
  transpose_w<<<dim3(16, 16), tb, 0, stream>>>(Wk, Wt_qkv + 1024 * 1024, 1024, 1024);
  transpose_w<<<dim3(16, 16), tb, 0, stream>>>(Wv, Wt_qkv + 2 * 1024 * 1024, 1024, 1024);
  transpose_w<<<dim3(16, 16), tb, 0, stream>>>(Wo, Wot, 1024, 1024);

  gemm_bt<<<dim3(64, 48), tb, 0, stream>>>(Xh, Wt_qkv, QKV, nullptr, 4096, 3072, 1024, 0);
  transpose_v<<<dim3(32, 32), tb, 0, stream>>>(QKV, Vt);
  attn<<<dim3(NB * NH * (SEQ / 16)), dim3(64), 0, stream>>>(QKV, Vt, Vec);
  gemm_bt<<<dim3(64, 16), tb, 0, stream>>>(Vec, Wot, nullptr, out, 4096, 1024, 1024, 1);
}

// Round 3
// 285.070 us; speedup vs baseline: 1.4237x; 1.4237x over previous
//
#include <hip/hip_runtime.h>
#include <hip/hip_bf16.h>

// fp32 I/O, fp16 MFMA compute (verified round 2: absmax 3.9e-3 vs thr 3.1e-2).

typedef __attribute__((ext_vector_type(8))) _Float16 vhalf8;  // 8 f16 (4 VGPRs)
typedef __attribute__((ext_vector_type(4))) float vfloat4;    // 4 fp32 acc

#define D_MODEL 1024
#define SEQ     2048
#define NB      2
#define NH      16
#define HD      64

// ---------------------------------------------------------------------------
// fp32 -> fp16 elementwise convert, 8 elems/thread.
// ---------------------------------------------------------------------------
__global__ __launch_bounds__(256) void cvt_f32_f16(
    const float* __restrict__ in, _Float16* __restrict__ out) {
  size_t i = ((size_t)blockIdx.x * 256 + threadIdx.x) * 8;
  float4 a = *(const float4*)&in[i];
  float4 b = *(const float4*)&in[i + 4];
  vhalf8 h;
  h[0] = (_Float16)a.x; h[1] = (_Float16)a.y;
  h[2] = (_Float16)a.z; h[3] = (_Float16)a.w;
  h[4] = (_Float16)b.x; h[5] = (_Float16)b.y;
  h[6] = (_Float16)b.z; h[7] = (_Float16)b.w;
  *(vhalf8*)&out[i] = h;
}

// ---------------------------------------------------------------------------
// Transpose + convert: out[c][r] = (f16)in[r][c].  in: R x C fp32.
// ---------------------------------------------------------------------------
__global__ __launch_bounds__(256) void transpose_w(
    const float* __restrict__ in, _Float16* __restrict__ out, int R, int C) {
  __shared__ _Float16 tile[64][65];
  int c0 = blockIdx.x * 64, r0 = blockIdx.y * 64;
  int t = threadIdx.x;
  int tc = t & 63, tr = t >> 6;
#pragma unroll
  for (int p = 0; p < 16; p++) {
    int r = tr + p * 4;
    tile[r][tc] = (_Float16)in[(size_t)(r0 + r) * C + c0 + tc];
  }
  __syncthreads();
#pragma unroll
  for (int p = 0; p < 16; p++) {
    int r = tr + p * 4;  // output row = input col
    out[(size_t)(c0 + r) * R + r0 + tc] = tile[tc][r];
  }
}

// ---------------------------------------------------------------------------
// V [(b,s)][2048 + h*64 + d] slice of QKV (f16) -> Vt [(b,h)][d][s]
// ---------------------------------------------------------------------------
__global__ __launch_bounds__(256) void transpose_v(
    const _Float16* __restrict__ QKV, _Float16* __restrict__ Vt) {
  __shared__ _Float16 tile[64][65];
  int bh = blockIdx.y;  // b*16 + h
  int b = bh >> 4, h = bh & 15;
  int s0 = blockIdx.x * 64;
  int t = threadIdx.x;
  int tc = t & 63, tr = t >> 6;
#pragma unroll
  for (int p = 0; p < 16; p++) {
    int s = tr + p * 4;
    tile[s][tc] = QKV[(size_t)(b * SEQ + s0 + s) * 3072 + 2048 + h * HD + tc];
  }
  __syncthreads();
#pragma unroll
  for (int p = 0; p < 16; p++) {
    int d = tr + p * 4;
    Vt[((size_t)bh * HD + d) * SEQ + s0 + tc] = tile[tc][d];
  }
}

// ---------------------------------------------------------------------------
// f16 GEMM, C[M][N] = A[M][K] @ Bt[N][K]^T.  64x64 tile, 4 waves, BK=32.
// ---------------------------------------------------------------------------
__global__ __launch_bounds__(256) void gemm_bt(
    const _Float16* __restrict__ A, const _Float16* __restrict__ Bt,
    _Float16* __restrict__ Ch, float* __restrict__ Cf,
    int M, int N, int K, int write_f32) {
  __shared__ _Float16 As[64][40];
  __shared__ _Float16 Bs[64][40];
  int m0 = blockIdx.x * 64, n0 = blockIdx.y * 64;
  int t = threadIdx.x;
  int lane = t & 63, wave = t >> 6;
  int wm = (wave >> 1) * 32, wn = (wave & 1) * 32;
  int col = lane & 15, quad = lane >> 4;
  int ldRow = t >> 2, ldChunk = (t & 3) * 8;

  vfloat4 acc[2][2];
#pragma unroll
  for (int i = 0; i < 2; i++)
#pragma unroll
    for (int j = 0; j < 2; j++) {
      acc[i][j][0] = 0.f; acc[i][j][1] = 0.f;
      acc[i][j][2] = 0.f; acc[i][j][3] = 0.f;
    }

  const size_t arow = (size_t)(m0 + ldRow) * K;
  const size_t brow = (size_t)(n0 + ldRow) * K;

  for (int k0 = 0; k0 < K; k0 += 32) {
    *(vhalf8*)&As[ldRow][ldChunk] = *(const vhalf8*)&A[arow + k0 + ldChunk];
    *(vhalf8*)&Bs[ldRow][ldChunk] = *(const vhalf8*)&Bt[brow + k0 + ldChunk];
    __syncthreads();
    vhalf8 a0 = *(const vhalf8*)&As[wm + col][quad * 8];
    vhalf8 a1 = *(const vhalf8*)&As[wm + 16 + col][quad * 8];
    vhalf8 b0 = *(const vhalf8*)&Bs[wn + col][quad * 8];
    vhalf8 b1 = *(const vhalf8*)&Bs[wn + 16 + col][quad * 8];
    acc[0][0] = __builtin_amdgcn_mfma_f32_16x16x32_f16(a0, b0, acc[0][0], 0, 0, 0);
    acc[0][1] = __builtin_amdgcn_mfma_f32_16x16x32_f16(a0, b1, acc[0][1], 0, 0, 0);
    acc[1][0] = __builtin_amdgcn_mfma_f32_16x16x32_f16(a1, b0, acc[1][0], 0, 0, 0);
    acc[1][1] = __builtin_amdgcn_mfma_f32_16x16x32_f16(a1, b1, acc[1][1], 0, 0, 0);
    __syncthreads();
  }

#pragma unroll
  for (int mi = 0; mi < 2; mi++)
#pragma unroll
    for (int ni = 0; ni < 2; ni++)
#pragma unroll
      for (int r = 0; r < 4; r++) {
        int m = m0 + wm + mi * 16 + quad * 4 + r;
        int n = n0 + wn + ni * 16 + col;
        if (write_f32)
          Cf[(size_t)m * N + n] = acc[mi][ni][r];
        else
          Ch[(size_t)m * N + n] = (_Float16)acc[mi][ni][r];
      }
}

// ---------------------------------------------------------------------------
// Flash attention, causal.  4 waves / block, 64 Q rows per block (16/wave),
// 64-key tiles staged in LDS (K rows + Vt rows), cooperative coalesced loads.
// QKV: [b*S][3072] f16 (Q 0..1023, K 1024..2047), Vt: [(b,h)][64][2048] f16.
// Out: Vec[b*S][1024] f16.
// ---------------------------------------------------------------------------
__global__ __launch_bounds__(256) void attn(
    const _Float16* __restrict__ QKV, const _Float16* __restrict__ Vt,
    _Float16* __restrict__ Vec) {
  int blk = blockIdx.x;
  int qt = blk & 31;           // 32 q-tiles of 64 rows
  int h = (blk >> 5) & 15;
  int b = blk >> 9;
  int q0 = qt * 64;

  const _Float16* Qb  = QKV + (size_t)(b * SEQ) * 3072 + h * HD;
  const _Float16* Kb  = QKV + (size_t)(b * SEQ) * 3072 + 1024 + h * HD;
  const _Float16* Vtb = Vt + (size_t)(b * NH + h) * HD * SEQ;

  int t = threadIdx.x;
  int lane = t & 63, wave = t >> 6;
  int col = lane & 15, quad = lane >> 4;
  int wq0 = q0 + wave * 16;    // this wave's 16 Q rows

  __shared__ _Float16 Ks[64][72];      // [key][dim]   72: 16B-aligned, 2-way banks
  __shared__ _Float16 Vs[64][72];      // [dim][key]
  __shared__ _Float16 Ps[4][16][72];   // per-wave P tile [qrow][key]

  // Q fragments for this wave (A-frag: row=col, k=quad*8+j; two 32-k chunks)
  vhalf8 qf0 = *(const vhalf8*)&Qb[(size_t)(wq0 + col) * 3072 + quad * 8];
  vhalf8 qf1 = *(const vhalf8*)&Qb[(size_t)(wq0 + col) * 3072 + 32 + quad * 8];

  vfloat4 o[4];
#pragma unroll
  for (int i = 0; i < 4; i++) { o[i][0]=0.f; o[i][1]=0.f; o[i][2]=0.f; o[i][3]=0.f; }
  float m_[4] = {-1e30f, -1e30f, -1e30f, -1e30f};
  float l_[4] = {0.f, 0.f, 0.f, 0.f};

  int srow = t >> 2;           // staging: row 0..63
  int scol = (t & 3) * 16;     // staging: 16-elem chunk

  for (int kb = 0; kb <= q0 + 63; kb += 64) {
    __syncthreads();  // previous iter's LDS reads done before restage
    {
      const _Float16* kg = &Kb[(size_t)(kb + srow) * 3072 + scol];
      *(vhalf8*)&Ks[srow][scol]     = *(const vhalf8*)kg;
      *(vhalf8*)&Ks[srow][scol + 8] = *(const vhalf8*)(kg + 8);
      const _Float16* vg = &Vtb[(size_t)srow * SEQ + kb + scol];
      *(vhalf8*)&Vs[srow][scol]     = *(const vhalf8*)vg;
      *(vhalf8*)&Vs[srow][scol + 8] = *(const vhalf8*)(vg + 8);
    }
    __syncthreads();

    if (kb <= wq0 + 15) {  // wave-uniform: skip fully-masked tiles
      // QK^T: 16 rows x 64 keys
      vfloat4 s[4];
#pragma unroll
      for (int hh = 0; hh < 4; hh++) {
        vhalf8 kf0 = *(const vhalf8*)&Ks[hh * 16 + col][quad * 8];
        vhalf8 kf1 = *(const vhalf8*)&Ks[hh * 16 + col][32 + quad * 8];
        vfloat4 z; z[0]=0.f; z[1]=0.f; z[2]=0.f; z[3]=0.f;
        z = __builtin_amdgcn_mfma_f32_16x16x32_f16(qf0, kf0, z, 0, 0, 0);
        z = __builtin_amdgcn_mfma_f32_16x16x32_f16(qf1, kf1, z, 0, 0, 0);
#pragma unroll
        for (int r = 0; r < 4; r++) z[r] *= 0.125f;  // 1/sqrt(64)
        s[hh] = z;
      }
      if (kb + 63 > wq0) {  // diagonal region: causal mask
#pragma unroll
        for (int hh = 0; hh < 4; hh++)
#pragma unroll
          for (int r = 0; r < 4; r++) {
            int key = kb + hh * 16 + col;
            int q = wq0 + quad * 4 + r;
            if (key > q) s[hh][r] = -1e30f;
          }
      }
      // online softmax per row (row = quad*4+r; 16 lanes of the quad share it)
#pragma unroll
      for (int r = 0; r < 4; r++) {
        float mt = fmaxf(fmaxf(s[0][r], s[1][r]), fmaxf(s[2][r], s[3][r]));
#pragma unroll
        for (int msk = 1; msk < 16; msk <<= 1) mt = fmaxf(mt, __shfl_xor(mt, msk, 64));
        float mnew = fmaxf(m_[r], mt);
        float alpha = __expf(m_[r] - mnew);
        float p0 = __expf(s[0][r] - mnew);
        float p1 = __expf(s[1][r] - mnew);
        float p2 = __expf(s[2][r] - mnew);
        float p3 = __expf(s[3][r] - mnew);
        float rs = (p0 + p1) + (p2 + p3);
#pragma unroll
        for (int msk = 1; msk < 16; msk <<= 1) rs += __shfl_xor(rs, msk, 64);
        l_[r] = l_[r] * alpha + rs;
        m_[r] = mnew;
#pragma unroll
        for (int tt = 0; tt < 4; tt++) o[tt][r] *= alpha;
        int row = quad * 4 + r;
        Ps[wave][row][col]      = (_Float16)p0;
        Ps[wave][row][16 + col] = (_Float16)p1;
        Ps[wave][row][32 + col] = (_Float16)p2;
        Ps[wave][row][48 + col] = (_Float16)p3;
      }
      // P write -> read is wave-local (Ps[wave]); only need LDS drain, no barrier
      __asm__ __volatile__("s_waitcnt lgkmcnt(0)" ::: "memory");
      vhalf8 pf0 = *(const vhalf8*)&Ps[wave][col][quad * 8];
      vhalf8 pf1 = *(const vhalf8*)&Ps[wave][col][32 + quad * 8];
#pragma unroll
      for (int tt = 0; tt < 4; tt++) {
        vhalf8 vf0 = *(const vhalf8*)&Vs[tt * 16 + col][quad * 8];
        vhalf8 vf1 = *(const vhalf8*)&Vs[tt * 16 + col][32 + quad * 8];
        o[tt] = __builtin_amdgcn_mfma_f32_16x16x32_f16(pf0, vf0, o[tt], 0, 0, 0);
        o[tt] = __builtin_amdgcn_mfma_f32_16x16x32_f16(pf1, vf1, o[tt], 0, 0, 0);
      }
    }
  }

  float inv_l[4];
#pragma unroll
  for (int r = 0; r < 4; r++) inv_l[r] = 1.0f / l_[r];
#pragma unroll
  for (int tt = 0; tt < 4; tt++)
#pragma unroll
    for (int r = 0; r < 4; r++) {
      int q = wq0 + quad * 4 + r;
      int d = tt * 16 + col;
      Vec[(size_t)(b * SEQ + q) * D_MODEL + h * HD + d] =
          (_Float16)(o[tt][r] * inv_l[r]);
    }
}

// ---------------------------------------------------------------------------
extern "C" void kernel_launch(void* const* d_in, const int* in_sizes, int n_in,
                              void* d_out, int out_size, void* d_ws, size_t ws_size,
                              hipStream_t stream) {
  const float* x  = (const float*)d_in[0];
  const float* Wq = (const float*)d_in[1];
  const float* Wk = (const float*)d_in[2];
  const float* Wv = (const float*)d_in[3];
  const float* Wo = (const float*)d_in[4];
  float* out = (float*)d_out;

  char* ws = (char*)d_ws;
  _Float16* Xh     = (_Float16*)ws;                    // [4096][1024]   8 MiB
  _Float16* Wt_qkv = (_Float16*)(ws + 8388608);        // [3072][1024]   6 MiB
  _Float16* Wot    = (_Float16*)(ws + 14680064);       // [1024][1024]   2 MiB
  _Float16* QKV    = (_Float16*)(ws + 16777216);       // [4096][3072]  24 MiB
  _Float16* Vt     = (_Float16*)(ws + 41943040);       // [32][64][2048] 8 MiB
  _Float16* Vec    = (_Float16*)(ws + 50331648);       // [4096][1024]   8 MiB

  dim3 tb(256);
  cvt_f32_f16<<<dim3(2048), tb, 0, stream>>>(x, Xh);
  transpose_w<<<dim3(16, 16), tb, 0, stream>>>(Wq, Wt_qkv, 1024, 1024);
  transpose_w<<<dim3(16, 16), tb, 0, stream>>>(Wk, Wt_qkv + 1024 * 1024, 1024, 1024);
  transpose_w<<<dim3(16, 16), tb, 0, stream>>>(Wv, Wt_qkv + 2 * 1024 * 1024, 1024, 1024);
  transpose_w<<<dim3(16, 16), tb, 0, stream>>>(Wo, Wot, 1024, 1024);

  gemm_bt<<<dim3(64, 48), tb, 0, stream>>>(Xh, Wt_qkv, QKV, nullptr, 4096, 3072, 1024, 0);
  transpose_v<<<dim3(32, 32), tb, 0, stream>>>(QKV, Vt);
  attn<<<dim3(NB * NH * (SEQ / 64)), tb, 0, stream>>>(QKV, Vt, Vec);
  gemm_bt<<<dim3(64, 16), tb, 0, stream>>>(Vec, Wot, nullptr, out, 4096, 1024, 1024, 1);
}

// Round 4
// 208.199 us; speedup vs baseline: 1.9494x; 1.3692x over previous
//
#include <hip/hip_runtime.h>
#include <hip/hip_bf16.h>

// fp32 I/O, fp16 MFMA compute (verified: absmax 3.9e-3 vs thr 3.1e-2).
// R4: fixed-offset softmax (C cancels in o/l), balanced qt schedule,
//     m97-style global_load_lds 128x128 GEMM.

typedef __attribute__((ext_vector_type(8))) _Float16 vhalf8;
typedef __attribute__((ext_vector_type(4))) _Float16 vhalf4;
typedef __attribute__((ext_vector_type(4))) float vfloat4;

#define D_MODEL 1024
#define SEQ     2048
#define NB      2
#define NH      16
#define HD      64

// exp(s/8 - 4) == exp2(s*K1 + K2); the -4 offset cancels in (sum p*V)/(sum p)
#define SCALE_K1 0.18033688f   // 0.125 * log2(e)
#define SCALE_K2 (-5.77078016f) // -4 * log2(e)

__device__ __forceinline__ void async16(const void* g, void* l) {
  __builtin_amdgcn_global_load_lds(
      (const __attribute__((address_space(1))) unsigned int*)g,
      (__attribute__((address_space(3))) unsigned int*)l, 16, 0, 0);
}

// ---------------------------------------------------------------------------
// fp32 -> fp16 convert, 8 elems/thread.
// ---------------------------------------------------------------------------
__global__ __launch_bounds__(256) void cvt_f32_f16(
    const float* __restrict__ in, _Float16* __restrict__ out) {
  size_t i = ((size_t)blockIdx.x * 256 + threadIdx.x) * 8;
  float4 a = *(const float4*)&in[i];
  float4 b = *(const float4*)&in[i + 4];
  vhalf8 h;
  h[0] = (_Float16)a.x; h[1] = (_Float16)a.y;
  h[2] = (_Float16)a.z; h[3] = (_Float16)a.w;
  h[4] = (_Float16)b.x; h[5] = (_Float16)b.y;
  h[6] = (_Float16)b.z; h[7] = (_Float16)b.w;
  *(vhalf8*)&out[i] = h;
}

// ---------------------------------------------------------------------------
// Transpose + convert: out[c][r] = (f16)in[r][c].  in: R x C fp32.
// ---------------------------------------------------------------------------
__global__ __launch_bounds__(256) void transpose_w(
    const float* __restrict__ in, _Float16* __restrict__ out, int R, int C) {
  __shared__ _Float16 tile[64][65];
  int c0 = blockIdx.x * 64, r0 = blockIdx.y * 64;
  int t = threadIdx.x;
  int tc = t & 63, tr = t >> 6;
#pragma unroll
  for (int p = 0; p < 16; p++) {
    int r = tr + p * 4;
    tile[r][tc] = (_Float16)in[(size_t)(r0 + r) * C + c0 + tc];
  }
  __syncthreads();
#pragma unroll
  for (int p = 0; p < 16; p++) {
    int r = tr + p * 4;
    out[(size_t)(c0 + r) * R + r0 + tc] = tile[tc][r];
  }
}

// ---------------------------------------------------------------------------
// V slice of QKV (f16) -> Vt [(b,h)][d][s]
// ---------------------------------------------------------------------------
__global__ __launch_bounds__(256) void transpose_v(
    const _Float16* __restrict__ QKV, _Float16* __restrict__ Vt) {
  __shared__ _Float16 tile[64][65];
  int bh = blockIdx.y;
  int b = bh >> 4, h = bh & 15;
  int s0 = blockIdx.x * 64;
  int t = threadIdx.x;
  int tc = t & 63, tr = t >> 6;
#pragma unroll
  for (int p = 0; p < 16; p++) {
    int s = tr + p * 4;
    tile[s][tc] = QKV[(size_t)(b * SEQ + s0 + s) * 3072 + 2048 + h * HD + tc];
  }
  __syncthreads();
#pragma unroll
  for (int p = 0; p < 16; p++) {
    int d = tr + p * 4;
    Vt[((size_t)bh * HD + d) * SEQ + s0 + tc] = tile[tc][d];
  }
}

// ---------------------------------------------------------------------------
// m97-style f16 GEMM: C[M][N] = A[M][K] @ Bt[N][K]^T.
// 128x128 tile, 4 waves (2x2 of 64x64), BK=32, global_load_lds width-16.
// LDS layout: unpadded row-major [128][32] per array (global_load_lds needs
// wave-uniform base + lane*16 contiguity; padding breaks it).
// ---------------------------------------------------------------------------
__global__ __launch_bounds__(256) void gemm128(
    const _Float16* __restrict__ A, const _Float16* __restrict__ Bt,
    _Float16* __restrict__ Ch, float* __restrict__ Cf,
    int M, int N, int K, int write_f32) {
  __shared__ _Float16 As[128 * 32];
  __shared__ _Float16 Bs[128 * 32];
  int m0 = blockIdx.x * 128, n0 = blockIdx.y * 128;
  int t = threadIdx.x;
  int lane = t & 63, wave = t >> 6;
  int wm = (wave >> 1) * 64, wn = (wave & 1) * 64;
  int col = lane & 15, quad = lane >> 4;

  // staging geometry: 16 chunks of 1KB; wave w owns chunks 4w..4w+3.
  // chunk c<8 -> As halves [c*512, +512); c>=8 -> Bs [(c-8)*512, +512).
  // lane L supplies the 16B at base + L*16: row = (c&7)*16 + L/4, kcol=(L&3)*8
  int srow = lane >> 2;
  int skc = (lane & 3) << 3;

  vfloat4 acc[4][4];
#pragma unroll
  for (int i = 0; i < 4; i++)
#pragma unroll
    for (int j = 0; j < 4; j++) {
      acc[i][j][0] = 0.f; acc[i][j][1] = 0.f;
      acc[i][j][2] = 0.f; acc[i][j][3] = 0.f;
    }

  for (int k0 = 0; k0 < K; k0 += 32) {
    __syncthreads();  // prior iter's LDS reads done before overwrite
#pragma unroll
    for (int j = 0; j < 4; j++) {
      int c = wave * 4 + j;
      int row = ((c & 7) << 4) + srow;
      if (c < 8)
        async16(&A[(size_t)(m0 + row) * K + k0 + skc], &As[c * 512]);
      else
        async16(&Bt[(size_t)(n0 + row) * K + k0 + skc], &Bs[(c - 8) * 512]);
    }
    __syncthreads();  // compiler drains vmcnt(0) before barrier => LDS valid

    vhalf8 af[4], bf[4];
#pragma unroll
    for (int i = 0; i < 4; i++) {
      af[i] = *(const vhalf8*)&As[(wm + i * 16 + col) * 32 + quad * 8];
      bf[i] = *(const vhalf8*)&Bs[(wn + i * 16 + col) * 32 + quad * 8];
    }
#pragma unroll
    for (int i = 0; i < 4; i++)
#pragma unroll
      for (int j = 0; j < 4; j++)
        acc[i][j] = __builtin_amdgcn_mfma_f32_16x16x32_f16(af[i], bf[j], acc[i][j], 0, 0, 0);
  }

#pragma unroll
  for (int i = 0; i < 4; i++)
#pragma unroll
    for (int j = 0; j < 4; j++)
#pragma unroll
      for (int r = 0; r < 4; r++) {
        int m = m0 + wm + i * 16 + quad * 4 + r;
        int n = n0 + wn + j * 16 + col;
        if (write_f32)
          Cf[(size_t)m * N + n] = acc[i][j][r];
        else
          Ch[(size_t)m * N + n] = (_Float16)acc[i][j][r];
      }
}

// ---------------------------------------------------------------------------
// Flash attention, causal, fixed-offset softmax (no running max/rescale).
// 4 waves / block, 64 Q rows (16/wave), 64-key LDS tiles.
// K rows staged permuted: slot 16*(kk&3)+(kk>>2) holds key kk, so frag tile
// hh at rows [hh*16+c] sees key 4c+hh => each lane's 4 P values are
// key-contiguous => single ds_write_b64 per row.
// ---------------------------------------------------------------------------
__global__ __launch_bounds__(256) void attn(
    const _Float16* __restrict__ QKV, const _Float16* __restrict__ Vt,
    _Float16* __restrict__ Vec) {
  int blk = blockIdx.x;
  // qt in HIGH bits + octet flip: CU's stride-256 set {j,j+8,j+16,j+24}
  // sums to 66 tile-iters regardless of j (balances causal triangle).
  int j = blk >> 5;
  int hb = blk & 31;
  int k8 = j >> 3, jp = j & 7;
  int qt = (k8 & 1) ? (8 * k8 + 7 - jp) : (8 * k8 + jp);
  int h = hb & 15;
  int b = hb >> 4;
  int q0 = qt * 64;

  const _Float16* Qb  = QKV + (size_t)(b * SEQ) * 3072 + h * HD;
  const _Float16* Kb  = QKV + (size_t)(b * SEQ) * 3072 + 1024 + h * HD;
  const _Float16* Vtb = Vt + (size_t)(b * NH + h) * HD * SEQ;

  int t = threadIdx.x;
  int lane = t & 63, wave = t >> 6;
  int col = lane & 15, quad = lane >> 4;
  int wq0 = q0 + wave * 16;

  __shared__ _Float16 Ks[64][72];
  __shared__ _Float16 Vs[64][72];
  __shared__ _Float16 Ps[4][16][72];

  vhalf8 qf0 = *(const vhalf8*)&Qb[(size_t)(wq0 + col) * 3072 + quad * 8];
  vhalf8 qf1 = *(const vhalf8*)&Qb[(size_t)(wq0 + col) * 3072 + 32 + quad * 8];

  vfloat4 o[4];
#pragma unroll
  for (int i = 0; i < 4; i++) { o[i][0]=0.f; o[i][1]=0.f; o[i][2]=0.f; o[i][3]=0.f; }
  float lsum[4] = {0.f, 0.f, 0.f, 0.f};

  int srow = t >> 2;            // key / dim row 0..63
  int scol = (t & 3) * 16;
  int kslot = ((srow & 3) << 4) + (srow >> 2);  // K permutation

  for (int kb = 0; kb <= q0 + 63; kb += 64) {
    __syncthreads();
    {
      const _Float16* kg = &Kb[(size_t)(kb + srow) * 3072 + scol];
      *(vhalf8*)&Ks[kslot][scol]     = *(const vhalf8*)kg;
      *(vhalf8*)&Ks[kslot][scol + 8] = *(const vhalf8*)(kg + 8);
      const _Float16* vg = &Vtb[(size_t)srow * SEQ + kb + scol];
      *(vhalf8*)&Vs[srow][scol]     = *(const vhalf8*)vg;
      *(vhalf8*)&Vs[srow][scol + 8] = *(const vhalf8*)(vg + 8);
    }
    __syncthreads();

    if (kb <= wq0 + 15) {
      vfloat4 s[4];
#pragma unroll
      for (int hh = 0; hh < 4; hh++) {
        vhalf8 kf0 = *(const vhalf8*)&Ks[hh * 16 + col][quad * 8];
        vhalf8 kf1 = *(const vhalf8*)&Ks[hh * 16 + col][32 + quad * 8];
        vfloat4 z; z[0]=0.f; z[1]=0.f; z[2]=0.f; z[3]=0.f;
        z = __builtin_amdgcn_mfma_f32_16x16x32_f16(qf0, kf0, z, 0, 0, 0);
        z = __builtin_amdgcn_mfma_f32_16x16x32_f16(qf1, kf1, z, 0, 0, 0);
        s[hh] = z;
      }
      bool diag = (kb + 63 > wq0);
#pragma unroll
      for (int r = 0; r < 4; r++) {
        int q = wq0 + quad * 4 + r;
        float p[4];
#pragma unroll
        for (int hh = 0; hh < 4; hh++) {
          float sc = fmaf(s[hh][r], SCALE_K1, SCALE_K2);
          if (diag && (kb + 4 * col + hh > q)) sc = -1e30f;
          p[hh] = __builtin_exp2f(sc);
        }
        lsum[r] += (p[0] + p[1]) + (p[2] + p[3]);
        vhalf4 ph;
        ph[0] = (_Float16)p[0]; ph[1] = (_Float16)p[1];
        ph[2] = (_Float16)p[2]; ph[3] = (_Float16)p[3];
        *(vhalf4*)&Ps[wave][quad * 4 + r][4 * col] = ph;
      }
      // P write->read is wave-local; LDS drain only, no block barrier
      __asm__ __volatile__("s_waitcnt lgkmcnt(0)" ::: "memory");
      vhalf8 pf0 = *(const vhalf8*)&Ps[wave][col][quad * 8];
      vhalf8 pf1 = *(const vhalf8*)&Ps[wave][col][32 + quad * 8];
#pragma unroll
      for (int tt = 0; tt < 4; tt++) {
        vhalf8 vf0 = *(const vhalf8*)&Vs[tt * 16 + col][quad * 8];
        vhalf8 vf1 = *(const vhalf8*)&Vs[tt * 16 + col][32 + quad * 8];
        o[tt] = __builtin_amdgcn_mfma_f32_16x16x32_f16(pf0, vf0, o[tt], 0, 0, 0);
        o[tt] = __builtin_amdgcn_mfma_f32_16x16x32_f16(pf1, vf1, o[tt], 0, 0, 0);
      }
    }
  }

  // one final l reduction across the 16 lanes sharing each row
  float inv_l[4];
#pragma unroll
  for (int r = 0; r < 4; r++) {
    float rs = lsum[r];
#pragma unroll
    for (int msk = 1; msk < 16; msk <<= 1) rs += __shfl_xor(rs, msk, 64);
    inv_l[r] = 1.0f / rs;
  }
#pragma unroll
  for (int tt = 0; tt < 4; tt++)
#pragma unroll
    for (int r = 0; r < 4; r++) {
      int q = wq0 + quad * 4 + r;
      int d = tt * 16 + col;
      Vec[(size_t)(b * SEQ + q) * D_MODEL + h * HD + d] =
          (_Float16)(o[tt][r] * inv_l[r]);
    }
}

// ---------------------------------------------------------------------------
extern "C" void kernel_launch(void* const* d_in, const int* in_sizes, int n_in,
                              void* d_out, int out_size, void* d_ws, size_t ws_size,
                              hipStream_t stream) {
  const float* x  = (const float*)d_in[0];
  const float* Wq = (const float*)d_in[1];
  const float* Wk = (const float*)d_in[2];
  const float* Wv = (const float*)d_in[3];
  const float* Wo = (const float*)d_in[4];
  float* out = (float*)d_out;

  char* ws = (char*)d_ws;
  _Float16* Xh     = (_Float16*)ws;                    // [4096][1024]   8 MiB
  _Float16* Wt_qkv = (_Float16*)(ws + 8388608);        // [3072][1024]   6 MiB
  _Float16* Wot    = (_Float16*)(ws + 14680064);       // [1024][1024]   2 MiB
  _Float16* QKV    = (_Float16*)(ws + 16777216);       // [4096][3072]  24 MiB
  _Float16* Vt     = (_Float16*)(ws + 41943040);       // [32][64][2048] 8 MiB
  _Float16* Vec    = (_Float16*)(ws + 50331648);       // [4096][1024]   8 MiB

  dim3 tb(256);
  cvt_f32_f16<<<dim3(2048), tb, 0, stream>>>(x, Xh);
  transpose_w<<<dim3(16, 16), tb, 0, stream>>>(Wq, Wt_qkv, 1024, 1024);
  transpose_w<<<dim3(16, 16), tb, 0, stream>>>(Wk, Wt_qkv + 1024 * 1024, 1024, 1024);
  transpose_w<<<dim3(16, 16), tb, 0, stream>>>(Wv, Wt_qkv + 2 * 1024 * 1024, 1024, 1024);
  transpose_w<<<dim3(16, 16), tb, 0, stream>>>(Wo, Wot, 1024, 1024);

  gemm128<<<dim3(32, 24), tb, 0, stream>>>(Xh, Wt_qkv, QKV, nullptr, 4096, 3072, 1024, 0);
  transpose_v<<<dim3(32, 32), tb, 0, stream>>>(QKV, Vt);
  attn<<<dim3(NB * NH * (SEQ / 64)), tb, 0, stream>>>(QKV, Vt, Vec);
  gemm128<<<dim3(32, 8), tb, 0, stream>>>(Vec, Wot, nullptr, out, 4096, 1024, 1024, 1);
}

// Round 6
// 193.366 us; speedup vs baseline: 2.0989x; 1.0767x over previous
//
#include <hip/hip_runtime.h>
#include <hip/hip_bf16.h>

// fp32 I/O, fp16 MFMA compute (verified: absmax 3.9e-3 vs thr 3.1e-2).
// R5b: same as R5 with cvt_pkrtz removed (type clash) — plain f16 casts.

typedef __attribute__((ext_vector_type(8))) _Float16 vhalf8;
typedef __attribute__((ext_vector_type(4))) _Float16 vhalf4;
typedef __attribute__((ext_vector_type(4))) float vfloat4;

#define D_MODEL 1024
#define SEQ     2048
#define NB      2
#define NH      16
#define HD      64

// softmax: exp(s/8) = exp2(s * 0.125*log2(e)); constant offset cancels in o/l.
#define SCALE_K1 0.18033688f

__device__ __forceinline__ void async16(const void* g, void* l) {
  __builtin_amdgcn_global_load_lds(
      (const __attribute__((address_space(1))) unsigned int*)g,
      (__attribute__((address_space(3))) unsigned int*)l, 16, 0, 0);
}

// ---------------------------------------------------------------------------
// fp32 -> fp16 convert, 8 elems/thread.
// ---------------------------------------------------------------------------
__global__ __launch_bounds__(256) void cvt_f32_f16(
    const float* __restrict__ in, _Float16* __restrict__ out) {
  size_t i = ((size_t)blockIdx.x * 256 + threadIdx.x) * 8;
  float4 a = *(const float4*)&in[i];
  float4 b = *(const float4*)&in[i + 4];
  vhalf8 h;
  h[0] = (_Float16)a.x; h[1] = (_Float16)a.y;
  h[2] = (_Float16)a.z; h[3] = (_Float16)a.w;
  h[4] = (_Float16)b.x; h[5] = (_Float16)b.y;
  h[6] = (_Float16)b.z; h[7] = (_Float16)b.w;
  *(vhalf8*)&out[i] = h;
}

// ---------------------------------------------------------------------------
// All 4 weight transposes in one launch: z selects source/dest.
// out[c][r] = (f16)in[r][c], 1024x1024 each.
// ---------------------------------------------------------------------------
__global__ __launch_bounds__(256) void transpose_w4(
    const float* __restrict__ Wq, const float* __restrict__ Wk,
    const float* __restrict__ Wv, const float* __restrict__ Wo,
    _Float16* __restrict__ Wt_qkv, _Float16* __restrict__ Wot) {
  __shared__ _Float16 tile[64][65];
  int z = blockIdx.z;
  const float* in = (z == 0) ? Wq : (z == 1) ? Wk : (z == 2) ? Wv : Wo;
  _Float16* out = (z < 3) ? (Wt_qkv + (size_t)z * 1024 * 1024) : Wot;
  int c0 = blockIdx.x * 64, r0 = blockIdx.y * 64;
  int t = threadIdx.x;
  int tc = t & 63, tr = t >> 6;
#pragma unroll
  for (int p = 0; p < 16; p++) {
    int r = tr + p * 4;
    tile[r][tc] = (_Float16)in[(size_t)(r0 + r) * 1024 + c0 + tc];
  }
  __syncthreads();
#pragma unroll
  for (int p = 0; p < 16; p++) {
    int r = tr + p * 4;
    out[(size_t)(c0 + r) * 1024 + r0 + tc] = tile[tc][r];
  }
}

// ---------------------------------------------------------------------------
// m97-style f16 GEMM: C[M][N] = A[M][K] @ Bt[N][K]^T.
// 128x128 tile, 4 waves (2x2 of 64x64), BK=32, global_load_lds width-16.
// mode 0: f16 out.  mode 1: f32 out.  mode 2 (QKV): f16 out, but V columns
// (n >= 2048) are written transposed into Vt[(b,h)][d][s] instead.
// ---------------------------------------------------------------------------
__global__ __launch_bounds__(256) void gemm128(
    const _Float16* __restrict__ A, const _Float16* __restrict__ Bt,
    _Float16* __restrict__ Ch, float* __restrict__ Cf,
    _Float16* __restrict__ Vt, int M, int N, int K, int mode) {
  __shared__ _Float16 As[128 * 32];
  __shared__ _Float16 Bs[128 * 32];
  int m0 = blockIdx.x * 128, n0 = blockIdx.y * 128;
  int t = threadIdx.x;
  int lane = t & 63, wave = t >> 6;
  int wm = (wave >> 1) * 64, wn = (wave & 1) * 64;
  int col = lane & 15, quad = lane >> 4;
  int srow = lane >> 2;
  int skc = (lane & 3) << 3;

  vfloat4 acc[4][4];
#pragma unroll
  for (int i = 0; i < 4; i++)
#pragma unroll
    for (int j = 0; j < 4; j++) {
      acc[i][j][0] = 0.f; acc[i][j][1] = 0.f;
      acc[i][j][2] = 0.f; acc[i][j][3] = 0.f;
    }

  for (int k0 = 0; k0 < K; k0 += 32) {
    __syncthreads();
#pragma unroll
    for (int j = 0; j < 4; j++) {
      int c = wave * 4 + j;
      int row = ((c & 7) << 4) + srow;
      if (c < 8)
        async16(&A[(size_t)(m0 + row) * K + k0 + skc], &As[c * 512]);
      else
        async16(&Bt[(size_t)(n0 + row) * K + k0 + skc], &Bs[(c - 8) * 512]);
    }
    __syncthreads();

    vhalf8 af[4], bf[4];
#pragma unroll
    for (int i = 0; i < 4; i++) {
      af[i] = *(const vhalf8*)&As[(wm + i * 16 + col) * 32 + quad * 8];
      bf[i] = *(const vhalf8*)&Bs[(wn + i * 16 + col) * 32 + quad * 8];
    }
#pragma unroll
    for (int i = 0; i < 4; i++)
#pragma unroll
      for (int j = 0; j < 4; j++)
        acc[i][j] = __builtin_amdgcn_mfma_f32_16x16x32_f16(af[i], bf[j], acc[i][j], 0, 0, 0);
  }

  bool vmode = (mode == 2) && (n0 >= 2048);
#pragma unroll
  for (int i = 0; i < 4; i++)
#pragma unroll
    for (int j = 0; j < 4; j++)
#pragma unroll
      for (int r = 0; r < 4; r++) {
        int m = m0 + wm + i * 16 + quad * 4 + r;
        int n = n0 + wn + j * 16 + col;
        if (mode == 1) {
          Cf[(size_t)m * N + n] = acc[i][j][r];
        } else if (vmode) {
          int nn = n - 2048;
          int hh = nn >> 6, dd = nn & 63;
          int bb = m >> 11, ss = m & 2047;
          Vt[(((size_t)bb * NH + hh) * HD + dd) * SEQ + ss] = (_Float16)acc[i][j][r];
        } else {
          Ch[(size_t)m * N + n] = (_Float16)acc[i][j][r];
        }
      }
}

// ---------------------------------------------------------------------------
// Flash attention, causal, fixed-offset softmax.  4 waves / block, 64 Q rows
// (16/wave), 64-key LDS tiles, register-prefetch staging, heavy-first order.
// K rows staged permuted (slot 16*(kk&3)+(kk>>2)) so each lane's 4 P values
// are key-contiguous (single b64 write).
// ---------------------------------------------------------------------------
__global__ __launch_bounds__(256) void attn(
    const _Float16* __restrict__ QKV, const _Float16* __restrict__ Vt,
    _Float16* __restrict__ Vec) {
  int blk = blockIdx.x;
  int qt = 31 - (blk >> 5);     // heavy blocks dispatch first; light backfill
  int hb = blk & 31;
  int h = hb & 15;
  int b = hb >> 4;
  int q0 = qt * 64;

  const _Float16* Qb  = QKV + (size_t)(b * SEQ) * 3072 + h * HD;
  const _Float16* Kb  = QKV + (size_t)(b * SEQ) * 3072 + 1024 + h * HD;
  const _Float16* Vtb = Vt + (size_t)(b * NH + h) * HD * SEQ;

  int t = threadIdx.x;
  int lane = t & 63, wave = t >> 6;
  int col = lane & 15, quad = lane >> 4;
  int wq0 = q0 + wave * 16;

  __shared__ _Float16 Ks[64][72];
  __shared__ _Float16 Vs[64][72];
  __shared__ _Float16 Ps[4][16][72];

  // Q fragments, pre-scaled by 0.125*log2(e) so softmax is bare exp2(s)
  vhalf8 qf0 = *(const vhalf8*)&Qb[(size_t)(wq0 + col) * 3072 + quad * 8];
  vhalf8 qf1 = *(const vhalf8*)&Qb[(size_t)(wq0 + col) * 3072 + 32 + quad * 8];
#pragma unroll
  for (int i = 0; i < 8; i++) {
    qf0[i] = qf0[i] * (_Float16)SCALE_K1;
    qf1[i] = qf1[i] * (_Float16)SCALE_K1;
  }

  vfloat4 o[4];
#pragma unroll
  for (int i = 0; i < 4; i++) { o[i][0]=0.f; o[i][1]=0.f; o[i][2]=0.f; o[i][3]=0.f; }
  float lsum[4] = {0.f, 0.f, 0.f, 0.f};

  int srow = t >> 2;
  int scol = (t & 3) * 16;
  int kslot = ((srow & 3) << 4) + (srow >> 2);  // K row permutation

  // prologue: prefetch tile kb=0 into registers
  vhalf8 kr0, kr1, vr0, vr1;
  {
    const _Float16* kg = &Kb[(size_t)srow * 3072 + scol];
    kr0 = *(const vhalf8*)kg; kr1 = *(const vhalf8*)(kg + 8);
    const _Float16* vg = &Vtb[(size_t)srow * SEQ + scol];
    vr0 = *(const vhalf8*)vg; vr1 = *(const vhalf8*)(vg + 8);
  }

  for (int kb = 0; kb <= q0 + 63; kb += 64) {
    // write prefetched tile to LDS
    *(vhalf8*)&Ks[kslot][scol]     = kr0;
    *(vhalf8*)&Ks[kslot][scol + 8] = kr1;
    *(vhalf8*)&Vs[srow][scol]      = vr0;
    *(vhalf8*)&Vs[srow][scol + 8]  = vr1;
    __syncthreads();

    // issue next tile's global loads; latency overlaps compute below
    if (kb < q0) {
      const _Float16* kg = &Kb[(size_t)(kb + 64 + srow) * 3072 + scol];
      kr0 = *(const vhalf8*)kg; kr1 = *(const vhalf8*)(kg + 8);
      const _Float16* vg = &Vtb[(size_t)srow * SEQ + kb + 64 + scol];
      vr0 = *(const vhalf8*)vg; vr1 = *(const vhalf8*)(vg + 8);
    }

    if (kb <= wq0 + 15) {
      vfloat4 s[4];
#pragma unroll
      for (int hh = 0; hh < 4; hh++) {
        vhalf8 kf0 = *(const vhalf8*)&Ks[hh * 16 + col][quad * 8];
        vhalf8 kf1 = *(const vhalf8*)&Ks[hh * 16 + col][32 + quad * 8];
        vfloat4 z; z[0]=0.f; z[1]=0.f; z[2]=0.f; z[3]=0.f;
        z = __builtin_amdgcn_mfma_f32_16x16x32_f16(qf0, kf0, z, 0, 0, 0);
        z = __builtin_amdgcn_mfma_f32_16x16x32_f16(qf1, kf1, z, 0, 0, 0);
        s[hh] = z;
      }
      bool diag = (kb + 63 > wq0);
#pragma unroll
      for (int r = 0; r < 4; r++) {
        int q = wq0 + quad * 4 + r;
        float p[4];
#pragma unroll
        for (int hh = 0; hh < 4; hh++) {
          float sc = s[hh][r];
          if (diag && (kb + 4 * col + hh > q)) sc = -1e30f;
          p[hh] = __builtin_exp2f(sc);
        }
        lsum[r] += (p[0] + p[1]) + (p[2] + p[3]);
        vhalf4 ph;
        ph[0] = (_Float16)p[0]; ph[1] = (_Float16)p[1];
        ph[2] = (_Float16)p[2]; ph[3] = (_Float16)p[3];
        *(vhalf4*)&Ps[wave][quad * 4 + r][4 * col] = ph;
      }
      // P write->read is wave-local; LDS drain only, no block barrier
      __asm__ __volatile__("s_waitcnt lgkmcnt(0)" ::: "memory");
      vhalf8 pf0 = *(const vhalf8*)&Ps[wave][col][quad * 8];
      vhalf8 pf1 = *(const vhalf8*)&Ps[wave][col][32 + quad * 8];
#pragma unroll
      for (int tt = 0; tt < 4; tt++) {
        vhalf8 vf0 = *(const vhalf8*)&Vs[tt * 16 + col][quad * 8];
        vhalf8 vf1 = *(const vhalf8*)&Vs[tt * 16 + col][32 + quad * 8];
        o[tt] = __builtin_amdgcn_mfma_f32_16x16x32_f16(pf0, vf0, o[tt], 0, 0, 0);
        o[tt] = __builtin_amdgcn_mfma_f32_16x16x32_f16(pf1, vf1, o[tt], 0, 0, 0);
      }
    }
    __syncthreads();
  }

  float inv_l[4];
#pragma unroll
  for (int r = 0; r < 4; r++) {
    float rs = lsum[r];
#pragma unroll
    for (int msk = 1; msk < 16; msk <<= 1) rs += __shfl_xor(rs, msk, 64);
    inv_l[r] = 1.0f / rs;
  }
#pragma unroll
  for (int tt = 0; tt < 4; tt++)
#pragma unroll
    for (int r = 0; r < 4; r++) {
      int q = wq0 + quad * 4 + r;
      int d = tt * 16 + col;
      Vec[(size_t)(b * SEQ + q) * D_MODEL + h * HD + d] =
          (_Float16)(o[tt][r] * inv_l[r]);
    }
}

// ---------------------------------------------------------------------------
extern "C" void kernel_launch(void* const* d_in, const int* in_sizes, int n_in,
                              void* d_out, int out_size, void* d_ws, size_t ws_size,
                              hipStream_t stream) {
  const float* x  = (const float*)d_in[0];
  const float* Wq = (const float*)d_in[1];
  const float* Wk = (const float*)d_in[2];
  const float* Wv = (const float*)d_in[3];
  const float* Wo = (const float*)d_in[4];
  float* out = (float*)d_out;

  char* ws = (char*)d_ws;
  _Float16* Xh     = (_Float16*)ws;                    // [4096][1024]   8 MiB
  _Float16* Wt_qkv = (_Float16*)(ws + 8388608);        // [3072][1024]   6 MiB
  _Float16* Wot    = (_Float16*)(ws + 14680064);       // [1024][1024]   2 MiB
  _Float16* QKV    = (_Float16*)(ws + 16777216);       // [4096][3072]  24 MiB (V region unused)
  _Float16* Vt     = (_Float16*)(ws + 41943040);       // [32][64][2048] 8 MiB
  _Float16* Vec    = (_Float16*)(ws + 50331648);       // [4096][1024]   8 MiB

  dim3 tb(256);
  cvt_f32_f16<<<dim3(2048), tb, 0, stream>>>(x, Xh);
  transpose_w4<<<dim3(16, 16, 4), tb, 0, stream>>>(Wq, Wk, Wv, Wo, Wt_qkv, Wot);

  gemm128<<<dim3(32, 24), tb, 0, stream>>>(Xh, Wt_qkv, QKV, nullptr, Vt,
                                           4096, 3072, 1024, 2);
  attn<<<dim3(NB * NH * (SEQ / 64)), tb, 0, stream>>>(QKV, Vt, Vec);
  gemm128<<<dim3(32, 8), tb, 0, stream>>>(Vec, Wot, nullptr, out, nullptr,
                                          4096, 1024, 1024, 1);
}

// Round 7
// 193.051 us; speedup vs baseline: 2.1023x; 1.0016x over previous
//
#include <hip/hip_runtime.h>
#include <hip/hip_bf16.h>

// fp32 I/O, fp16 MFMA compute (verified: absmax 3.9e-3 vs thr 3.1e-2).
// R7: 512-thread attn blocks (8 waves share K/V staging), XOR-swizzled K
//     staging (kills 4-way bank conflict), merged prep kernel, BN-templated
//     GEMM (out-proj at 128x64 for 2 blocks/CU).

typedef __attribute__((ext_vector_type(8))) _Float16 vhalf8;
typedef __attribute__((ext_vector_type(4))) _Float16 vhalf4;
typedef __attribute__((ext_vector_type(4))) float vfloat4;

#define D_MODEL 1024
#define SEQ     2048
#define NB      2
#define NH      16
#define HD      64

// softmax: exp(s/8) = exp2(s * 0.125*log2(e)); constant offset cancels in o/l.
#define SCALE_K1 0.18033688f

__device__ __forceinline__ void async16(const void* g, void* l) {
  __builtin_amdgcn_global_load_lds(
      (const __attribute__((address_space(1))) unsigned int*)g,
      (__attribute__((address_space(3))) unsigned int*)l, 16, 0, 0);
}

// ---------------------------------------------------------------------------
// prep: z<4 -> weight transpose+convert planes; z==4 -> x fp32->fp16 convert.
// ---------------------------------------------------------------------------
__global__ __launch_bounds__(256) void prep(
    const float* __restrict__ x,
    const float* __restrict__ Wq, const float* __restrict__ Wk,
    const float* __restrict__ Wv, const float* __restrict__ Wo,
    _Float16* __restrict__ Xh, _Float16* __restrict__ Wt_qkv,
    _Float16* __restrict__ Wot) {
  int z = blockIdx.z;
  int t = threadIdx.x;
  if (z == 4) {  // x convert: 4096*1024 elems, 256 blocks * 8 passes
    int id = blockIdx.y * 16 + blockIdx.x;
#pragma unroll
    for (int pass = 0; pass < 8; pass++) {
      size_t i = ((size_t)(pass * 256 + id) * 256 + t) * 8;
      float4 a = *(const float4*)&x[i];
      float4 b = *(const float4*)&x[i + 4];
      vhalf8 h;
      h[0] = (_Float16)a.x; h[1] = (_Float16)a.y;
      h[2] = (_Float16)a.z; h[3] = (_Float16)a.w;
      h[4] = (_Float16)b.x; h[5] = (_Float16)b.y;
      h[6] = (_Float16)b.z; h[7] = (_Float16)b.w;
      *(vhalf8*)&Xh[i] = h;
    }
    return;
  }
  __shared__ _Float16 tile[64][65];
  const float* in = (z == 0) ? Wq : (z == 1) ? Wk : (z == 2) ? Wv : Wo;
  _Float16* out = (z < 3) ? (Wt_qkv + (size_t)z * 1024 * 1024) : Wot;
  int c0 = blockIdx.x * 64, r0 = blockIdx.y * 64;
  int tc = t & 63, tr = t >> 6;
#pragma unroll
  for (int p = 0; p < 16; p++) {
    int r = tr + p * 4;
    tile[r][tc] = (_Float16)in[(size_t)(r0 + r) * 1024 + c0 + tc];
  }
  __syncthreads();
#pragma unroll
  for (int p = 0; p < 16; p++) {
    int r = tr + p * 4;
    out[(size_t)(c0 + r) * 1024 + r0 + tc] = tile[tc][r];
  }
}

// ---------------------------------------------------------------------------
// m97-style f16 GEMM: C[M][N] = A[M][K] @ Bt[N][K]^T.
// 128xBN tile, 4 waves (2x2 of 64x(BN/2)), BK=32, global_load_lds width-16.
// mode 0: f16 out.  mode 1: f32 out.  mode 2 (QKV): f16 out, V cols
// (n >= 2048) written transposed into Vt[(b,h)][d][s].
// ---------------------------------------------------------------------------
template <int BN>
__global__ __launch_bounds__(256) void gemm128(
    const _Float16* __restrict__ A, const _Float16* __restrict__ Bt,
    _Float16* __restrict__ Ch, float* __restrict__ Cf,
    _Float16* __restrict__ Vt, int M, int N, int K, int mode) {
  constexpr int NC = 8 + BN / 16;   // 1KB staging chunks total
  constexpr int CPW = NC / 4;       // chunks per wave
  constexpr int JN = BN / 32;       // 16-col j-tiles per wave
  __shared__ _Float16 As[128 * 32];
  __shared__ _Float16 Bs[BN * 32];
  int m0 = blockIdx.x * 128, n0 = blockIdx.y * BN;
  int t = threadIdx.x;
  int lane = t & 63, wave = t >> 6;
  int wm = (wave >> 1) * 64, wn = (wave & 1) * (BN / 2);
  int col = lane & 15, quad = lane >> 4;
  int srow = lane >> 2;
  int skc = (lane & 3) << 3;

  vfloat4 acc[4][JN];
#pragma unroll
  for (int i = 0; i < 4; i++)
#pragma unroll
    for (int j = 0; j < JN; j++) {
      acc[i][j][0] = 0.f; acc[i][j][1] = 0.f;
      acc[i][j][2] = 0.f; acc[i][j][3] = 0.f;
    }

  for (int k0 = 0; k0 < K; k0 += 32) {
    __syncthreads();
#pragma unroll
    for (int j = 0; j < CPW; j++) {
      int c = wave * CPW + j;
      int row = ((c < 8) ? c : (c - 8)) * 16 + srow;
      if (c < 8)
        async16(&A[(size_t)(m0 + row) * K + k0 + skc], &As[c * 512]);
      else
        async16(&Bt[(size_t)(n0 + row) * K + k0 + skc], &Bs[(c - 8) * 512]);
    }
    __syncthreads();

    vhalf8 af[4], bf[JN];
#pragma unroll
    for (int i = 0; i < 4; i++)
      af[i] = *(const vhalf8*)&As[(wm + i * 16 + col) * 32 + quad * 8];
#pragma unroll
    for (int j = 0; j < JN; j++)
      bf[j] = *(const vhalf8*)&Bs[(wn + j * 16 + col) * 32 + quad * 8];
#pragma unroll
    for (int i = 0; i < 4; i++)
#pragma unroll
      for (int j = 0; j < JN; j++)
        acc[i][j] = __builtin_amdgcn_mfma_f32_16x16x32_f16(af[i], bf[j], acc[i][j], 0, 0, 0);
  }

  bool vmode = (mode == 2) && (n0 >= 2048);
#pragma unroll
  for (int i = 0; i < 4; i++)
#pragma unroll
    for (int j = 0; j < JN; j++)
#pragma unroll
      for (int r = 0; r < 4; r++) {
        int m = m0 + wm + i * 16 + quad * 4 + r;
        int n = n0 + wn + j * 16 + col;
        if (mode == 1) {
          Cf[(size_t)m * N + n] = acc[i][j][r];
        } else if (vmode) {
          int nn = n - 2048;
          int hh = nn >> 6, dd = nn & 63;
          int bb = m >> 11, ss = m & 2047;
          Vt[(((size_t)bb * NH + hh) * HD + dd) * SEQ + ss] = (_Float16)acc[i][j][r];
        } else {
          Ch[(size_t)m * N + n] = (_Float16)acc[i][j][r];
        }
      }
}

// ---------------------------------------------------------------------------
// Flash attention, causal, fixed-offset softmax.  8 waves (512 thr) / block,
// 128 Q rows per block (16/wave), 64-key LDS tiles shared by all 8 waves,
// register-prefetch staging, heavy-first dispatch order.
// K rows staged permuted (slot 16*(kk&3)+(kk>>2)) so each lane's 4 P values
// are key-contiguous; staging columns XOR-swizzled by (srow&3)*16 to kill
// the 4-way bank conflict (slots {0,16,32,48} share bank base at 144B rows).
// ---------------------------------------------------------------------------
__global__ __launch_bounds__(512) void attn(
    const _Float16* __restrict__ QKV, const _Float16* __restrict__ Vt,
    _Float16* __restrict__ Vec) {
  int blk = blockIdx.x;
  int qt = 15 - (blk >> 5);     // heavy blocks first; light backfill
  int hb = blk & 31;
  int h = hb & 15;
  int b = hb >> 4;
  int q0 = qt * 128;

  const _Float16* Qb  = QKV + (size_t)(b * SEQ) * 3072 + h * HD;
  const _Float16* Kb  = QKV + (size_t)(b * SEQ) * 3072 + 1024 + h * HD;
  const _Float16* Vtb = Vt + (size_t)(b * NH + h) * HD * SEQ;

  int t = threadIdx.x;
  int lane = t & 63, wave = t >> 6;
  int col = lane & 15, quad = lane >> 4;
  int wq0 = q0 + wave * 16;

  __shared__ _Float16 Ks[64][72];
  __shared__ _Float16 Vs[64][72];
  __shared__ _Float16 Ps[8][16][72];

  // Q fragments, pre-scaled by 0.125*log2(e) so softmax is bare exp2(s)
  vhalf8 qf0 = *(const vhalf8*)&Qb[(size_t)(wq0 + col) * 3072 + quad * 8];
  vhalf8 qf1 = *(const vhalf8*)&Qb[(size_t)(wq0 + col) * 3072 + 32 + quad * 8];
#pragma unroll
  for (int i = 0; i < 8; i++) {
    qf0[i] = qf0[i] * (_Float16)SCALE_K1;
    qf1[i] = qf1[i] * (_Float16)SCALE_K1;
  }

  vfloat4 o[4];
#pragma unroll
  for (int i = 0; i < 4; i++) { o[i][0]=0.f; o[i][1]=0.f; o[i][2]=0.f; o[i][3]=0.f; }
  float lsum[4] = {0.f, 0.f, 0.f, 0.f};

  // staging: 512 threads, one vhalf8 of K and one of V each
  int srow = t >> 3;                         // 0..63
  int scol = (t & 7) * 8;                    // 8-elem chunk
  int kslot = ((srow & 3) << 4) + (srow >> 2);
  int kcol = scol ^ ((srow & 3) << 4);       // XOR swizzle

  // prologue: prefetch tile kb=0
  vhalf8 kr, vr;
  kr = *(const vhalf8*)&Kb[(size_t)srow * 3072 + scol];
  vr = *(const vhalf8*)&Vtb[(size_t)srow * SEQ + scol];

  for (int kb = 0; kb <= q0 + 127; kb += 64) {
    *(vhalf8*)&Ks[kslot][kcol] = kr;
    *(vhalf8*)&Vs[srow][scol]  = vr;
    __syncthreads();

    if (kb < q0 + 64) {  // prefetch next tile; overlaps compute
      kr = *(const vhalf8*)&Kb[(size_t)(kb + 64 + srow) * 3072 + scol];
      vr = *(const vhalf8*)&Vtb[(size_t)srow * SEQ + kb + 64 + scol];
    }

    if (kb <= wq0 + 15) {
      vfloat4 s[4];
#pragma unroll
      for (int hh = 0; hh < 4; hh++) {
        int sw = hh << 4;  // un-swizzle
        vhalf8 kf0 = *(const vhalf8*)&Ks[hh * 16 + col][(quad * 8) ^ sw];
        vhalf8 kf1 = *(const vhalf8*)&Ks[hh * 16 + col][(32 + quad * 8) ^ sw];
        vfloat4 z; z[0]=0.f; z[1]=0.f; z[2]=0.f; z[3]=0.f;
        z = __builtin_amdgcn_mfma_f32_16x16x32_f16(qf0, kf0, z, 0, 0, 0);
        z = __builtin_amdgcn_mfma_f32_16x16x32_f16(qf1, kf1, z, 0, 0, 0);
        s[hh] = z;
      }
      bool diag = (kb + 63 > wq0);
#pragma unroll
      for (int r = 0; r < 4; r++) {
        int q = wq0 + quad * 4 + r;
        float p[4];
#pragma unroll
        for (int hh = 0; hh < 4; hh++) {
          float sc = s[hh][r];
          if (diag && (kb + 4 * col + hh > q)) sc = -1e30f;
          p[hh] = __builtin_exp2f(sc);
        }
        lsum[r] += (p[0] + p[1]) + (p[2] + p[3]);
        vhalf4 ph;
        ph[0] = (_Float16)p[0]; ph[1] = (_Float16)p[1];
        ph[2] = (_Float16)p[2]; ph[3] = (_Float16)p[3];
        *(vhalf4*)&Ps[wave][quad * 4 + r][4 * col] = ph;
      }
      // P write->read is wave-local; LDS drain only, no block barrier
      __asm__ __volatile__("s_waitcnt lgkmcnt(0)" ::: "memory");
      vhalf8 pf0 = *(const vhalf8*)&Ps[wave][col][quad * 8];
      vhalf8 pf1 = *(const vhalf8*)&Ps[wave][col][32 + quad * 8];
#pragma unroll
      for (int tt = 0; tt < 4; tt++) {
        vhalf8 vf0 = *(const vhalf8*)&Vs[tt * 16 + col][quad * 8];
        vhalf8 vf1 = *(const vhalf8*)&Vs[tt * 16 + col][32 + quad * 8];
        o[tt] = __builtin_amdgcn_mfma_f32_16x16x32_f16(pf0, vf0, o[tt], 0, 0, 0);
        o[tt] = __builtin_amdgcn_mfma_f32_16x16x32_f16(pf1, vf1, o[tt], 0, 0, 0);
      }
    }
    __syncthreads();
  }

  float inv_l[4];
#pragma unroll
  for (int r = 0; r < 4; r++) {
    float rs = lsum[r];
#pragma unroll
    for (int msk = 1; msk < 16; msk <<= 1) rs += __shfl_xor(rs, msk, 64);
    inv_l[r] = 1.0f / rs;
  }
#pragma unroll
  for (int tt = 0; tt < 4; tt++)
#pragma unroll
    for (int r = 0; r < 4; r++) {
      int q = wq0 + quad * 4 + r;
      int d = tt * 16 + col;
      Vec[(size_t)(b * SEQ + q) * D_MODEL + h * HD + d] =
          (_Float16)(o[tt][r] * inv_l[r]);
    }
}

// ---------------------------------------------------------------------------
extern "C" void kernel_launch(void* const* d_in, const int* in_sizes, int n_in,
                              void* d_out, int out_size, void* d_ws, size_t ws_size,
                              hipStream_t stream) {
  const float* x  = (const float*)d_in[0];
  const float* Wq = (const float*)d_in[1];
  const float* Wk = (const float*)d_in[2];
  const float* Wv = (const float*)d_in[3];
  const float* Wo = (const float*)d_in[4];
  float* out = (float*)d_out;

  char* ws = (char*)d_ws;
  _Float16* Xh     = (_Float16*)ws;                    // [4096][1024]   8 MiB
  _Float16* Wt_qkv = (_Float16*)(ws + 8388608);        // [3072][1024]   6 MiB
  _Float16* Wot    = (_Float16*)(ws + 14680064);       // [1024][1024]   2 MiB
  _Float16* QKV    = (_Float16*)(ws + 16777216);       // [4096][3072]  24 MiB (V region unused)
  _Float16* Vt     = (_Float16*)(ws + 41943040);       // [32][64][2048] 8 MiB
  _Float16* Vec    = (_Float16*)(ws + 50331648);       // [4096][1024]   8 MiB

  dim3 tb(256);
  prep<<<dim3(16, 16, 5), tb, 0, stream>>>(x, Wq, Wk, Wv, Wo, Xh, Wt_qkv, Wot);
  gemm128<128><<<dim3(32, 24), tb, 0, stream>>>(Xh, Wt_qkv, QKV, nullptr, Vt,
                                                4096, 3072, 1024, 2);
  attn<<<dim3(512), dim3(512), 0, stream>>>(QKV, Vt, Vec);
  gemm128<64><<<dim3(32, 16), tb, 0, stream>>>(Vec, Wot, nullptr, out, nullptr,
                                               4096, 1024, 1024, 1);
}